// Round 3
// baseline (129.563 us; speedup 1.0000x reference)
//
#include <hip/hip_runtime.h>
#include <stdint.h>

// LIF scan, chunk-parallel with warm-up convergence.
// v' = fma(v, 0.95, I); s = sigmoid(10(v'-1)); hard = v'>1; v'' = v'*(1-s)
// Outputs (f32, concat): spikes[B*L], hard_latency[B], soft_latency[B]
//
// R3: TILE_T 32->64 (256B/row stores kill the 2.36x HBM write amplification
//     seen in R2), single 16KB LDS buffer reused in-place (I tile -> S tile),
//     WARM 256->128 (absmax margin is ~4 orders of magnitude).

constexpr float TH_   = 1.0f;
constexpr float LEAK  = 0.95f;                   // 1 - 1/tau
constexpr float KL2E  = 14.426950408889634f;     // K * log2(e)
constexpr int   LDIM   = 4096;
constexpr int   TILE_T = 64;                     // timesteps per LDS tile
constexpr int   CH     = TILE_T / 4;             // 16 float4 chunks per row
constexpr int   NCHUNK = 16;                     // time-parallel chunks
constexpr int   WARM   = 128;                    // warm-up steps

__device__ __forceinline__ float exp2_fast(float x) {
#if __has_builtin(__builtin_amdgcn_exp2f)
  return __builtin_amdgcn_exp2f(x);
#else
  return exp2f(x);
#endif
}

// One LIF step. Returns surrogate s; updates v (and latf when LAT).
template <bool LAT>
__device__ __forceinline__ float lif_step(float& v, float Iv, float tf, float& latf) {
  v = fmaf(v, LEAK, Iv);                       // Euler, fused
  float e = exp2_fast(fmaf(-KL2E, v, KL2E));   // exp(-K*(v-TH)) in exp2 domain
  float s = __builtin_amdgcn_rcpf(1.0f + e);   // sigmoid
  if (LAT) {
    if (v > TH_) latf = fminf(latf, tf);       // first hard crossing (pre-reset v)
  }
  v = fmaf(-s, v, v);                          // v *= (1 - s)
  return s;
}

// ---- 64 rows x 64 cols staging, float4-chunk XOR swizzle ----
// LDS: float4 buf[64*16]; row r, position p holds logical chunk p ^ (r&15).

__device__ __forceinline__ void load_tile(float4* stg, const float* __restrict__ I,
                                          int row0, int t0, int lane) {
  const int c     = lane & 15;                 // chunk 0..15
  const int rbase = lane >> 4;                 // 0..3
#pragma unroll
  for (int i = 0; i < CH; ++i) {
    const int r = 4 * i + rbase;
    stg[i] = *reinterpret_cast<const float4*>(
        I + (size_t)(row0 + r) * LDIM + t0 + 4 * c);   // 16 lanes = 256B coalesced
  }
}

__device__ __forceinline__ void write_tile(float4* buf, const float4* stg, int lane) {
  const int c     = lane & 15;
  const int rbase = lane >> 4;
#pragma unroll
  for (int i = 0; i < CH; ++i) {
    const int r = 4 * i + rbase;
    buf[r * CH + (c ^ (r & 15))] = stg[i];
  }
}

__device__ __forceinline__ void drain_tile(const float4* buf, float* __restrict__ gOut,
                                           int lane) {
  const int c     = lane & 15;
  const int rbase = lane >> 4;
#pragma unroll
  for (int i = 0; i < CH; ++i) {
    const int r = 4 * i + rbase;
    float4 vd = buf[r * CH + (c ^ (r & 15))];
    *reinterpret_cast<float4*>(gOut + (size_t)r * LDIM + 4 * c) = vd;  // 256B/row
  }
}

// In-place: reads I group j+1 (prefetch), writes S group j back to the same
// buffer. Per-lane the read pointer is one slot ahead of the write pointer.
template <bool LAT>
__device__ __forceinline__ void process_tile(float4* __restrict__ buf, int lane,
                                             float& v, float& latf,
                                             float& ss, float& sst, float& tf) {
  const int m    = lane & 15;
  const int base = lane * CH;
  float4 c = buf[base + (0 ^ m)];
#pragma unroll
  for (int j = 0; j < CH; ++j) {
    float4 Ij = c;
    if (j + 1 < CH) c = buf[base + ((j + 1) ^ m)];
    float4 S;
    S.x = lif_step<LAT>(v, Ij.x, tf + 0.0f, latf);
    S.y = lif_step<LAT>(v, Ij.y, tf + 1.0f, latf);
    S.z = lif_step<LAT>(v, Ij.z, tf + 2.0f, latf);
    S.w = lif_step<LAT>(v, Ij.w, tf + 3.0f, latf);
    float g = (S.x + S.y) + (S.z + S.w);       // Σ s over the 4 steps
    ss += g;
    sst = fmaf(g, tf, sst);                    // Σ s·t decomposition
    sst += S.y;
    sst = fmaf(2.0f, S.z, sst);
    sst = fmaf(3.0f, S.w, sst);
    tf += 4.0f;
    buf[base + (j ^ m)] = S;                   // in-place S write
  }
}

__device__ __forceinline__ void process_warm(const float4* __restrict__ buf, int lane,
                                             float& v) {
  const int m    = lane & 15;
  const int base = lane * CH;
  float dummy = 0.0f;
  float4 c = buf[base + (0 ^ m)];
#pragma unroll
  for (int j = 0; j < CH; ++j) {
    float4 Ij = c;
    if (j + 1 < CH) c = buf[base + ((j + 1) ^ m)];
    lif_step<false>(v, Ij.x, 0.0f, dummy);
    lif_step<false>(v, Ij.y, 0.0f, dummy);
    lif_step<false>(v, Ij.z, 0.0f, dummy);
    lif_step<false>(v, Ij.w, 0.0f, dummy);
  }
}

// DIRECT=false: per-(chunk,row) partials into pA(Σs)/pB(Σs·t)/pL(first-t).
// DIRECT=true : single-chunk fallback; pA<-soft, pL<-hard directly.
template <bool DIRECT>
__global__ void __launch_bounds__(64) lif_scan(
    const float* __restrict__ I, float* __restrict__ spikes,
    float* __restrict__ pA, float* __restrict__ pB, float* __restrict__ pL,
    int B, int own, int warm) {
  __shared__ float4 buf[64 * CH];    // 16 KiB, in-place I -> S

  const int lane  = threadIdx.x;
  const int row0  = blockIdx.x * 64;
  const int row   = row0 + lane;
  const int chunk = blockIdx.y;

  const int t_own  = chunk * own;
  const int t_beg  = (chunk == 0) ? 0 : t_own - warm;
  const int nwarm  = (t_own - t_beg) / TILE_T;
  const int ntile  = nwarm + own / TILE_T;

  float v = 0.0f;
  float latf = (float)LDIM;
  float ss = 0.0f, sst = 0.0f;
  float tf = (float)t_own;           // absolute step index for owned region
  float4 stg[CH];

  load_tile(stg, I, row0, t_beg, lane);
  write_tile(buf, stg, lane);

  for (int k = 0; k < ntile; ++k) {
    if (k + 1 < ntile)
      load_tile(stg, I, row0, t_beg + (k + 1) * TILE_T, lane);  // in flight under compute

    if (k < nwarm) {
      process_warm(buf, lane, v);
    } else {
      const bool need_lat = !__all(latf < (float)LDIM);
      if (need_lat) process_tile<true >(buf, lane, v, latf, ss, sst, tf);
      else          process_tile<false>(buf, lane, v, latf, ss, sst, tf);
      drain_tile(buf, spikes + (size_t)row0 * LDIM + t_beg + k * TILE_T, lane);
    }

    if (k + 1 < ntile)
      write_tile(buf, stg, lane);    // vmcnt wait lands here, after compute+drain
  }

  if (DIRECT) {
    pL[row] = latf;
    pA[row] = sst / (ss + 1e-6f);
  } else {
    const size_t o = (size_t)chunk * B + row;
    pA[o] = ss;
    pB[o] = sst;
    pL[o] = latf;
  }
}

extern "C" __global__ void __launch_bounds__(256) lif_reduce(
    const float* __restrict__ pA, const float* __restrict__ pB,
    const float* __restrict__ pL, float* __restrict__ hard,
    float* __restrict__ soft, int B) {
  const int r = blockIdx.x * 256 + threadIdx.x;
  if (r >= B) return;
  float a = 0.0f, b = 0.0f, l = (float)LDIM;
  for (int c = 0; c < NCHUNK; ++c) {
    a += pA[(size_t)c * B + r];
    b += pB[(size_t)c * B + r];
    l = fminf(l, pL[(size_t)c * B + r]);
  }
  hard[r] = l;
  soft[r] = b / (a + 1e-6f);
}

extern "C" void kernel_launch(void* const* d_in, const int* in_sizes, int n_in,
                              void* d_out, int out_size, void* d_ws, size_t ws_size,
                              hipStream_t stream) {
  const float* I = (const float*)d_in[0];
  const int B = in_sizes[0] / LDIM;            // 8192
  float* out    = (float*)d_out;
  float* spikes = out;
  float* hard   = out + (size_t)B * LDIM;
  float* soft   = hard + B;

  const size_t need = (size_t)3 * NCHUNK * B * sizeof(float);
  if (ws_size >= need) {
    float* pA = (float*)d_ws;
    float* pB = pA + (size_t)NCHUNK * B;
    float* pL = pB + (size_t)NCHUNK * B;
    hipLaunchKernelGGL((lif_scan<false>), dim3(B / 64, NCHUNK), dim3(64), 0, stream,
                       I, spikes, pA, pB, pL, B, LDIM / NCHUNK, WARM);
    hipLaunchKernelGGL(lif_reduce, dim3((B + 255) / 256), dim3(256), 0, stream,
                       pA, pB, pL, hard, soft, B);
  } else {
    // fallback: single chunk, direct outputs (hard<-pL, soft<-pA)
    hipLaunchKernelGGL((lif_scan<true>), dim3(B / 64, 1), dim3(64), 0, stream,
                       I, spikes, soft, soft, hard, B, LDIM, 0);
  }
}

// Round 4
// 68.237 us; speedup vs baseline: 1.8987x; 1.8987x over previous
//
#include <hip/hip_runtime.h>
#include <stdint.h>

// LIF scan, chunk-parallel with warm-up convergence.
// v' = fma(v, 0.95, I); s = sigmoid(10(v'-1)); hard = v'>1; v'' = v'*(1-s)
// Outputs (f32, concat): spikes[B*L], hard_latency[B], soft_latency[B]
//
// R4: kill the stg[16] register-staging array (R3's VGPR=88 proves it spilled
//     to scratch -> the 179MB write excess). global_load_lds width=16 stages
//     I directly into LDS: linear LDS dest + pre-swizzled per-lane global src.
//     Single 16KB buffer, in-place I->S, one wave per block (no barriers).

constexpr float TH_   = 1.0f;
constexpr float LEAK  = 0.95f;                   // 1 - 1/tau
constexpr float KL2E  = 14.426950408889634f;     // K * log2(e)
constexpr int   LDIM   = 4096;
constexpr int   TILE_T = 64;                     // timesteps per LDS tile
constexpr int   CH     = TILE_T / 4;             // 16 float4 chunks per row
constexpr int   NCHUNK = 16;                     // time-parallel chunks
constexpr int   WARM   = 128;                    // warm-up steps

typedef __attribute__((address_space(1))) const unsigned int glob_u32;
typedef __attribute__((address_space(3))) unsigned int lds_u32;

__device__ __forceinline__ float exp2_fast(float x) {
#if __has_builtin(__builtin_amdgcn_exp2f)
  return __builtin_amdgcn_exp2f(x);
#else
  return exp2f(x);
#endif
}

// One LIF step. Returns surrogate s; updates v (and latf when LAT).
template <bool LAT>
__device__ __forceinline__ float lif_step(float& v, float Iv, float tf, float& latf) {
  v = fmaf(v, LEAK, Iv);                       // Euler, fused
  float e = exp2_fast(fmaf(-KL2E, v, KL2E));   // exp(-K*(v-TH)) in exp2 domain
  float s = __builtin_amdgcn_rcpf(1.0f + e);   // sigmoid
  if (LAT) {
    if (v > TH_) latf = fminf(latf, tf);       // first hard crossing (pre-reset v)
  }
  v = fmaf(-s, v, v);                          // v *= (1 - s)
  return s;
}

// ---- 64 rows x 64 cols tile, float4-chunk XOR swizzle ----
// LDS: float4 buf[64*16]; linear slot s=(r*16+p) holds logical chunk c=p^(r&15)
// of row r. global_load_lds writes slots linearly (base + lane*16B), so the
// per-lane GLOBAL address is pre-swizzled to match (rule #21: both-sides).

__device__ __forceinline__ void stage_tile(const float* __restrict__ I, float4* buf,
                                           int row0, int t0, int lane) {
  const int sub = lane >> 4;                   // 0..3
  const int p   = lane & 15;                   // slot position within row
#pragma unroll
  for (int i = 0; i < CH; ++i) {
    const int r = 4 * i + sub;                 // row this lane's slot belongs to
    const int c = p ^ (r & 15);                // logical chunk stored at position p
    const float* src = I + (size_t)(row0 + r) * LDIM + t0 + 4 * c;
    __builtin_amdgcn_global_load_lds((glob_u32*)src, (lds_u32*)(buf + i * 64),
                                     16, 0, 0);   // 64 lanes x 16B -> 1KB slab
  }
}

__device__ __forceinline__ void drain_tile(const float4* buf, float* __restrict__ gOut,
                                           int lane) {
  const int c     = lane & 15;
  const int rbase = lane >> 4;
#pragma unroll
  for (int i = 0; i < CH; ++i) {
    const int r = 4 * i + rbase;
    float4 vd = buf[r * CH + (c ^ (r & 15))];  // swizzled ds_read_b128
    *reinterpret_cast<float4*>(gOut + (size_t)r * LDIM + 4 * c) = vd;  // 256B/row
  }
}

// In-place: reads I group j+1 (prefetch), writes S group j back to the same
// buffer. Per-lane the read pointer is one slot ahead of the write pointer.
template <bool LAT>
__device__ __forceinline__ void process_tile(float4* __restrict__ buf, int lane,
                                             float& v, float& latf,
                                             float& ss, float& sst, float& tf) {
  const int m    = lane & 15;
  const int base = lane * CH;
  float4 c = buf[base + (0 ^ m)];
#pragma unroll
  for (int j = 0; j < CH; ++j) {
    float4 Ij = c;
    if (j + 1 < CH) c = buf[base + ((j + 1) ^ m)];
    float4 S;
    S.x = lif_step<LAT>(v, Ij.x, tf + 0.0f, latf);
    S.y = lif_step<LAT>(v, Ij.y, tf + 1.0f, latf);
    S.z = lif_step<LAT>(v, Ij.z, tf + 2.0f, latf);
    S.w = lif_step<LAT>(v, Ij.w, tf + 3.0f, latf);
    float g = (S.x + S.y) + (S.z + S.w);       // Σ s over the 4 steps
    ss += g;
    sst = fmaf(g, tf, sst);                    // Σ s·t decomposition
    sst += S.y;
    sst = fmaf(2.0f, S.z, sst);
    sst = fmaf(3.0f, S.w, sst);
    tf += 4.0f;
    buf[base + (j ^ m)] = S;                   // in-place S write
  }
}

__device__ __forceinline__ void process_warm(const float4* __restrict__ buf, int lane,
                                             float& v) {
  const int m    = lane & 15;
  const int base = lane * CH;
  float dummy = 0.0f;
  float4 c = buf[base + (0 ^ m)];
#pragma unroll
  for (int j = 0; j < CH; ++j) {
    float4 Ij = c;
    if (j + 1 < CH) c = buf[base + ((j + 1) ^ m)];
    lif_step<false>(v, Ij.x, 0.0f, dummy);
    lif_step<false>(v, Ij.y, 0.0f, dummy);
    lif_step<false>(v, Ij.z, 0.0f, dummy);
    lif_step<false>(v, Ij.w, 0.0f, dummy);
  }
}

// DIRECT=false: per-(chunk,row) partials into pA(Σs)/pB(Σs·t)/pL(first-t).
// DIRECT=true : single-chunk fallback; pA<-soft, pL<-hard directly.
template <bool DIRECT>
__global__ void __launch_bounds__(64) lif_scan(
    const float* __restrict__ I, float* __restrict__ spikes,
    float* __restrict__ pA, float* __restrict__ pB, float* __restrict__ pL,
    int B, int own, int warm) {
  __shared__ float4 buf[64 * CH];    // 16 KiB, in-place I -> S

  const int lane  = threadIdx.x;
  const int row0  = blockIdx.x * 64;
  const int row   = row0 + lane;
  const int chunk = blockIdx.y;

  const int t_own  = chunk * own;
  const int t_beg  = (chunk == 0) ? 0 : t_own - warm;
  const int nwarm  = (t_own - t_beg) / TILE_T;
  const int ntile  = nwarm + own / TILE_T;

  float v = 0.0f;
  float latf = (float)LDIM;
  float ss = 0.0f, sst = 0.0f;
  float tf = (float)t_own;           // absolute step index for owned region

  stage_tile(I, buf, row0, t_beg, lane);

  for (int k = 0; k < ntile; ++k) {
    asm volatile("s_waitcnt vmcnt(0)" ::: "memory");   // tile k landed in LDS

    if (k < nwarm) {
      process_warm(buf, lane, v);
    } else {
      const bool need_lat = !__all(latf < (float)LDIM);
      if (need_lat) process_tile<true >(buf, lane, v, latf, ss, sst, tf);
      else          process_tile<false>(buf, lane, v, latf, ss, sst, tf);
      drain_tile(buf, spikes + (size_t)row0 * LDIM + t_beg + k * TILE_T, lane);
    }

    // All LDS reads of tile k have executed (their data fed stores/VALU above);
    // safe to restage into the same buffer. Single wave -> no barrier needed.
    if (k + 1 < ntile)
      stage_tile(I, buf, row0, t_beg + (k + 1) * TILE_T, lane);
  }

  if (DIRECT) {
    pL[row] = latf;
    pA[row] = sst / (ss + 1e-6f);
  } else {
    const size_t o = (size_t)chunk * B + row;
    pA[o] = ss;
    pB[o] = sst;
    pL[o] = latf;
  }
}

extern "C" __global__ void __launch_bounds__(256) lif_reduce(
    const float* __restrict__ pA, const float* __restrict__ pB,
    const float* __restrict__ pL, float* __restrict__ hard,
    float* __restrict__ soft, int B) {
  const int r = blockIdx.x * 256 + threadIdx.x;
  if (r >= B) return;
  float a = 0.0f, b = 0.0f, l = (float)LDIM;
  for (int c = 0; c < NCHUNK; ++c) {
    a += pA[(size_t)c * B + r];
    b += pB[(size_t)c * B + r];
    l = fminf(l, pL[(size_t)c * B + r]);
  }
  hard[r] = l;
  soft[r] = b / (a + 1e-6f);
}

extern "C" void kernel_launch(void* const* d_in, const int* in_sizes, int n_in,
                              void* d_out, int out_size, void* d_ws, size_t ws_size,
                              hipStream_t stream) {
  const float* I = (const float*)d_in[0];
  const int B = in_sizes[0] / LDIM;            // 8192
  float* out    = (float*)d_out;
  float* spikes = out;
  float* hard   = out + (size_t)B * LDIM;
  float* soft   = hard + B;

  const size_t need = (size_t)3 * NCHUNK * B * sizeof(float);
  if (ws_size >= need) {
    float* pA = (float*)d_ws;
    float* pB = pA + (size_t)NCHUNK * B;
    float* pL = pB + (size_t)NCHUNK * B;
    hipLaunchKernelGGL((lif_scan<false>), dim3(B / 64, NCHUNK), dim3(64), 0, stream,
                       I, spikes, pA, pB, pL, B, LDIM / NCHUNK, WARM);
    hipLaunchKernelGGL(lif_reduce, dim3((B + 255) / 256), dim3(256), 0, stream,
                       pA, pB, pL, hard, soft, B);
  } else {
    // fallback: single chunk, direct outputs (hard<-pL, soft<-pA)
    hipLaunchKernelGGL((lif_scan<true>), dim3(B / 64, 1), dim3(64), 0, stream,
                       I, spikes, soft, soft, hard, B, LDIM, 0);
  }
}